// Round 13
// baseline (64.842 us; speedup 1.0000x reference)
//
#include <hip/hip_runtime.h>
#include <math.h>

typedef short short8 __attribute__((ext_vector_type(8)));
typedef float f32x4 __attribute__((ext_vector_type(4)));

#define B_N 2048
#define NKM 9
#define CP 512          // C*4, cp = c*4 + p  (p fastest)
#define KU 128          // MUL
#define STG 132         // LDS staging row stride (ushorts): 8B-aligned, bank-spread
#define INV_SQRT_MUL 0.08838834764831845f   // 1/sqrt(128)
#define INV_SQRT_4C  0.04419417382415922f   // 1/sqrt(512)

// persistent device scratch; fully rewritten every launch before any read
__device__ ushort g_xb1[NKM * B_N * KU];          // [km][b][u] bf16
__device__ ushort g_xb2[NKM * B_N * KU];
__device__ ushort g_W1bt[3 * CP * KU];            // [l][cp][u] bf16, * 1/sqrt(128)
__device__ ushort g_W2bt[3 * CP * KU];
__device__ ushort g_Woutbt[3 * KU * CP];          // [l][u][cp] bf16, * 1/sqrt(512)
__device__ ushort g_cb[(size_t)B_N * NKM * CP];   // c_out, [b][km][cp] bf16

__device__ __forceinline__ ushort f2b(float f) {
    uint u = __float_as_uint(f);
    uint r = (u + 0x7fffu + ((u >> 16) & 1u)) >> 16;   // RNE
    return (ushort)r;
}
__device__ __forceinline__ float pk_lo(uint u) { return __uint_as_float(u << 16); }
__device__ __forceinline__ float pk_hi(uint u) { return __uint_as_float(u & 0xffff0000u); }
__device__ __forceinline__ int l_of_km(int km) { return (km >= 4) ? 2 : (km >= 1 ? 1 : 0); }

// ---------------------------------------------------------------------------
// Gaunt tensor (real orthonormal SH, l<=2): closed form; per-i constexpr
// sub-tables -> constexpr loop bounds -> full unroll -> literal reg indices.
// ---------------------------------------------------------------------------
__host__ __device__ constexpr int lof(int n) { return n >= 4 ? 2 : (n >= 1 ? 1 : 0); }
__host__ __device__ constexpr int mof(int n) { int l = lof(n); return n - l * l - l; }
__host__ __device__ constexpr bool gaunt_nz(int a, int b, int c) {
    int la = lof(a), lb = lof(b), lc = lof(c);
    if ((la + lb + lc) & 1) return false;
    if (lc > la + lb || la > lb + lc || lb > lc + la) return false;
    int ma = mof(a), mb = mof(b), mc = mof(c);
    int neg = (ma < 0) + (mb < 0) + (mc < 0);
    if (neg & 1) return false;
    int A = ma < 0 ? -ma : ma, Bm = mb < 0 ? -mb : mb, Cm = mc < 0 ? -mc : mc;
    return (A + Bm == Cm) || (Bm + Cm == A) || (Cm + A == Bm);
}
__host__ __device__ constexpr float gaunt_val(int a, int b, int c) {
    int x = a, y = b, z = c, t = 0;
    if (x > y) { t = x; x = y; y = t; }
    if (y > z) { t = y; y = z; z = t; }
    if (x > y) { t = x; x = y; y = t; }
    const float C00 = 0.28209479177387814f;   // 1/(2*sqrt(pi))
    const float A_  = 0.12615662610100802f;
    const float B_  = 0.25231325220201604f;
    const float C_  = 0.21850968611841584f;
    const float D_  = 0.18022375157286857f;
    const float E_  = 0.09011187578643429f;
    const float F_  = 0.15607834722743988f;
    if (x == 0) return C00;
    if (y <= 3) {
        if (z == 6) return (y == 2) ? B_ : -A_;
        if (z == 8) return (x == 1) ? -C_ : C_;
        return C_;
    }
    if (x == 4) return (y == 4) ? -D_ : F_;
    if (x == 5) return (z == 6) ? E_ : -F_;
    if (x == 6) return (y == 6) ? D_ : ((y == 7) ? E_ : -D_);
    return F_;
}
struct IEnt { int k, j; float v; };
struct ITab { IEnt e[16]; int n; };
__host__ __device__ constexpr ITab make_it(int ii) {
    ITab t{};
    for (int k = 0; k < 9; ++k)
        for (int j = 0; j < 9; ++j)
            if (gaunt_nz(k, ii, j)) {
                t.e[t.n].k = k; t.e[t.n].j = j; t.e[t.n].v = gaunt_val(k, ii, j);
                ++t.n;
            }
    return t;
}

// per-km middle step: accumulate this i-plane's Gaunt terms into o
template <int I>
__device__ __forceinline__ void mid_step(const ushort* __restrict__ c1s,
                                         int mb, int mc,
                                         const float (&f2v)[2][9][4],
                                         float (&o)[2][4][9]) {
    constexpr ITab T = make_it(I);
    #pragma unroll
    for (int un = 0; un < 2; ++un) {
        int cc = mc + un * 16;
        uint2 v = *(const uint2*)&c1s[mb * STG + cc * 4];
        float a0 = pk_lo(v.x), a1 = pk_hi(v.x);
        float a2 = pk_lo(v.y), a3 = pk_hi(v.y);
        #pragma unroll
        for (int e = 0; e < T.n; ++e) {          // constexpr bound -> full unroll
            const int   k = T.e[e].k, j = T.e[e].j;
            const float g = T.e[e].v;
            float d0 = f2v[un][j][0], d1 = f2v[un][j][1];
            float d2 = f2v[un][j][2], d3 = f2v[un][j][3];
            o[un][0][k] = fmaf(g, a0 * d0, o[un][0][k]);
            o[un][1][k] = fmaf(g, fmaf(a2, d3, -(a3 * d2)), o[un][1][k]);
            o[un][2][k] = fmaf(g, fmaf(a3, d1, -(a1 * d3)), o[un][2][k]);
            o[un][3][k] = fmaf(g, fmaf(a1, d2, -(a2 * d1)), o[un][3][k]);
        }
    }
}

// ---------------------------------------------------------------------------
// prep_combined (unchanged, validated):
//   blocks [0, B_N):        x transpose->bf16 for row b, + zero out tail cols
//   blocks [B_N, B_N+768):  W1/W2/Wout bf16 repack with scales folded in
// ---------------------------------------------------------------------------
__global__ __launch_bounds__(256) void prep_kernel(const float* __restrict__ x1,
                                                   const float* __restrict__ x2,
                                                   const float* __restrict__ W1,
                                                   const float* __restrict__ W2,
                                                   const float* __restrict__ Wout,
                                                   float* __restrict__ out) {
    int bid = blockIdx.x, tid = threadIdx.x;
    if (bid >= B_N) {
        int idx = (bid - B_N) * 256 + tid;       // < 3*512*128 = 196608
        int l = idx >> 16;
        int r = idx & 65535;
        {   // W1bt/W2bt [l][cp][u] <- W[l][u][cp]
            int cp = r >> 7, u = r & 127;
            size_t src = (size_t)l * 65536 + (size_t)u * 512 + cp;
            g_W1bt[idx] = f2b(W1[src] * INV_SQRT_MUL);
            g_W2bt[idx] = f2b(W2[src] * INV_SQRT_MUL);
        }
        {   // Woutbt [l][u][cp] <- Wout[l][cp][u]
            int u = r >> 9, cp = r & 511;
            g_Woutbt[idx] = f2b(Wout[(size_t)l * 65536 + (size_t)cp * 128 + u] * INV_SQRT_4C);
        }
        return;
    }
    int b = bid;
    __shared__ float L1[2048], L2[2048];
    const float4* r1 = (const float4*)(x1 + (size_t)b * 2048);
    const float4* r2 = (const float4*)(x2 + (size_t)b * 2048);
    #pragma unroll
    for (int i = 0; i < 2; ++i) {
        int q = i * 256 + tid;
        *(float4*)&L1[q * 4] = r1[q];
        *(float4*)&L2[q * 4] = r2[q];
    }
    float4 z = make_float4(0.f, 0.f, 0.f, 0.f);
    if (tid < 224) *(float4*)&out[(size_t)b * 2048 + 1152 + tid * 4] = z;
    __syncthreads();
    #pragma unroll
    for (int i = 0; i < 9; ++i) {
        int e = i * 256 + tid;                    // < 2304 = 2 fields * 9 km * 128 u
        int field = e >= 1152;
        int r = e - field * 1152;
        int km = r >> 7, u = r & 127;
        int l = l_of_km(km);
        int col = l * l * 128 + u * (2 * l + 1) + (km - l * l);
        float v = field ? L2[col] : L1[col];
        ushort* dst = field ? g_xb2 : g_xb1;
        dst[(size_t)km * (B_N * KU) + (size_t)b * KU + u] = f2b(v);
    }
}

// ---------------------------------------------------------------------------
// cmid helpers: A 16x128 load (1 chunk/thread), B 128x128 load, 16x128x128 GEMM
// ---------------------------------------------------------------------------
__device__ __forceinline__ void load_A16(const ushort* __restrict__ xa, int b0,
                                         int tid, ushort* As) {
    int row = tid >> 4, kg = tid & 15;
    int dst = row * 128 + ((kg ^ (row & 7)) << 3);
    *(short8*)&As[dst] = *(const short8*)&xa[(size_t)(b0 + row) * KU + (kg << 3)];
}
__device__ __forceinline__ void load_B128(const ushort* __restrict__ wb, int n0,
                                          int tid, ushort* Bs) {
    #pragma unroll
    for (int it = 0; it < 8; ++it) {
        int i = it * 256 + tid;
        int row = i >> 4, kg = i & 15;
        int dst = row * 128 + ((kg ^ (row & 7)) << 3);
        *(short8*)&Bs[dst] = *(const short8*)&wb[(size_t)(n0 + row) * KU + (kg << 3)];
    }
}
__device__ __forceinline__ void gemm16x128(const ushort* As, const ushort* Bs,
                                           int lane, int wid, ushort* stage) {
    f32x4 acc0 = (f32x4){0.f, 0.f, 0.f, 0.f};
    f32x4 acc1 = (f32x4){0.f, 0.f, 0.f, 0.f};
    #pragma unroll
    for (int ks = 0; ks < 4; ++ks) {
        int kg = ks * 4 + (lane >> 4);
        int ar = lane & 15;
        short8 a = *(const short8*)&As[ar * 128 + ((kg ^ (ar & 7)) << 3)];
        int br0 = wid * 32 + (lane & 15);
        short8 b0v = *(const short8*)&Bs[br0 * 128 + ((kg ^ (br0 & 7)) << 3)];
        acc0 = __builtin_amdgcn_mfma_f32_16x16x32_bf16(a, b0v, acc0, 0, 0, 0);
        int br1 = br0 + 16;
        short8 b1v = *(const short8*)&Bs[br1 * 128 + ((kg ^ (br1 & 7)) << 3)];
        acc1 = __builtin_amdgcn_mfma_f32_16x16x32_bf16(a, b1v, acc1, 0, 0, 0);
    }
    #pragma unroll
    for (int r = 0; r < 4; ++r) {
        int row = ((lane >> 4) << 2) + r;       // b-row 0..15
        stage[row * STG + wid * 32 + (lane & 15)]      = f2b(acc0[r]);
        stage[row * STG + wid * 32 + 16 + (lane & 15)] = f2b(acc1[r]);
    }
}

// ---------------------------------------------------------------------------
// cmid: fused stage-1 GEMMs + Gaunt middle. Block = (16 b-rows x 128 cp).
// Field-2 c2 staged in LDS (all 9 km) -> regs; field-1 km-at-a-time with
// interleaved mid_step<KM>. Writes only g_cb (c1/c2 never touch HBM).
// grid (4 cp-tiles, 128 b-tiles), 256 threads, ~79 KB LDS -> 2 blocks/CU.
// ---------------------------------------------------------------------------
__global__ __launch_bounds__(256) void cmid_kernel() {
    __shared__ ushort As[16 * 128];        //  4 KB
    __shared__ ushort Bs[128 * 128];       // 32 KB
    __shared__ ushort c1s[16 * STG];       //  4.2 KB
    __shared__ ushort c2s[9][16 * STG];    // 38 KB

    int tid = threadIdx.x;
    int n0 = blockIdx.x * 128, b0 = blockIdx.y * 16;
    int lane = tid & 63, wid = tid >> 6;
    int mb = tid >> 4, mc = tid & 15;      // middle unit coords: (b=mb, c=mc/mc+16)

#define F2_STEP(KM) \
    load_A16(g_xb2 + (size_t)(KM) * (B_N * KU), b0, tid, As); \
    __syncthreads(); \
    gemm16x128(As, Bs, lane, wid, &c2s[KM][0]); \
    __syncthreads();

    load_B128(g_W2bt + 0 * 65536, n0, tid, Bs);
    F2_STEP(0)
    load_B128(g_W2bt + 1 * 65536, n0, tid, Bs);
    F2_STEP(1) F2_STEP(2) F2_STEP(3)
    load_B128(g_W2bt + 2 * 65536, n0, tid, Bs);
    F2_STEP(4) F2_STEP(5) F2_STEP(6) F2_STEP(7) F2_STEP(8)
#undef F2_STEP

    // preload this thread's 2 units' c2 (all 9 km), unpacked to f32
    float f2v[2][9][4];
    #pragma unroll
    for (int k = 0; k < 9; ++k) {
        #pragma unroll
        for (int un = 0; un < 2; ++un) {
            int cc = mc + un * 16;
            uint2 v = *(const uint2*)&c2s[k][mb * STG + cc * 4];
            f2v[un][k][0] = pk_lo(v.x); f2v[un][k][1] = pk_hi(v.x);
            f2v[un][k][2] = pk_lo(v.y); f2v[un][k][3] = pk_hi(v.y);
        }
    }

    float o[2][4][9];
    #pragma unroll
    for (int un = 0; un < 2; ++un)
        #pragma unroll
        for (int p = 0; p < 4; ++p)
            #pragma unroll
            for (int k = 0; k < 9; ++k) o[un][p][k] = 0.f;

#define F1_STEP(KM) \
    load_A16(g_xb1 + (size_t)(KM) * (B_N * KU), b0, tid, As); \
    __syncthreads(); \
    gemm16x128(As, Bs, lane, wid, c1s); \
    __syncthreads(); \
    mid_step<KM>(c1s, mb, mc, f2v, o);

    load_B128(g_W1bt + 0 * 65536, n0, tid, Bs);
    F1_STEP(0)
    load_B128(g_W1bt + 1 * 65536, n0, tid, Bs);
    F1_STEP(1) F1_STEP(2) F1_STEP(3)
    load_B128(g_W1bt + 2 * 65536, n0, tid, Bs);
    F1_STEP(4) F1_STEP(5) F1_STEP(6) F1_STEP(7) F1_STEP(8)
#undef F1_STEP

    // write cb: per unit 9 x 8B coalesced stores
    #pragma unroll
    for (int un = 0; un < 2; ++un) {
        int cc = mc + un * 16;
        ushort* w = g_cb + (size_t)(b0 + mb) * (NKM * CP) + n0 + cc * 4;
        #pragma unroll
        for (int k = 0; k < 9; ++k) {
            uint2 st;
            st.x = (uint)f2b(o[un][0][k]) | ((uint)f2b(o[un][1][k]) << 16);
            st.y = (uint)f2b(o[un][2][k]) | ((uint)f2b(o[un][3][k]) << 16);
            *(uint2*)&w[(size_t)k * CP] = st;
        }
    }
}

// ---------------------------------------------------------------------------
// out_gemm (unchanged, validated): out = cb x Woutbt, 64x128 tile, K=512
// ---------------------------------------------------------------------------
__global__ __launch_bounds__(256) void out_gemm_kernel(float* __restrict__ out) {
    __shared__ ushort Aso[64 * 128];
    __shared__ ushort Bso[128 * 128];
    int tid = threadIdx.x;
    int km = blockIdx.y;
    int l = l_of_km(km);
    int mi = km - l * l, d = 2 * l + 1, OFF = 128 * l * l;
    int b0 = blockIdx.x * 64;

    int lane = tid & 63, wid = tid >> 6, wr = wid >> 1, wc = wid & 1;
    f32x4 acc[2][4];
    #pragma unroll
    for (int i = 0; i < 2; ++i)
        #pragma unroll
        for (int j = 0; j < 4; ++j) acc[i][j] = (f32x4){0.f, 0.f, 0.f, 0.f};

    for (int kc = 0; kc < 4; ++kc) {
        #pragma unroll
        for (int it = 0; it < 4; ++it) {
            int i = it * 256 + tid;
            int row = i >> 4, kg = i & 15;
            int dst = row * 128 + ((kg ^ (row & 7)) << 3);
            *(short8*)&Aso[dst] = *(const short8*)&g_cb[(size_t)(b0 + row) * (NKM * CP)
                                                       + (size_t)km * CP + kc * 128 + (kg << 3)];
        }
        #pragma unroll
        for (int it = 0; it < 8; ++it) {
            int i = it * 256 + tid;
            int row = i >> 4, kg = i & 15;
            int dst = row * 128 + ((kg ^ (row & 7)) << 3);
            *(short8*)&Bso[dst] = *(const short8*)&g_Woutbt[(size_t)l * 65536
                                                       + (size_t)row * CP + kc * 128 + (kg << 3)];
        }
        __syncthreads();
        #pragma unroll
        for (int ks = 0; ks < 4; ++ks) {
            int kg = ks * 4 + (lane >> 4);
            short8 a[2], b[4];
            #pragma unroll
            for (int i = 0; i < 2; ++i) {
                int row = wr * 32 + i * 16 + (lane & 15);
                a[i] = *(const short8*)&Aso[row * 128 + ((kg ^ (row & 7)) << 3)];
            }
            #pragma unroll
            for (int j = 0; j < 4; ++j) {
                int row = wc * 64 + j * 16 + (lane & 15);
                b[j] = *(const short8*)&Bso[row * 128 + ((kg ^ (row & 7)) << 3)];
            }
            #pragma unroll
            for (int i = 0; i < 2; ++i)
                #pragma unroll
                for (int j = 0; j < 4; ++j)
                    acc[i][j] = __builtin_amdgcn_mfma_f32_16x16x32_bf16(a[i], b[j], acc[i][j], 0, 0, 0);
        }
        __syncthreads();
    }

    #pragma unroll
    for (int i = 0; i < 2; ++i)
        #pragma unroll
        for (int j = 0; j < 4; ++j)
            #pragma unroll
            for (int r = 0; r < 4; ++r) {
                int row = b0 + wr * 32 + i * 16 + ((lane >> 4) << 2) + r;
                int u   = wc * 64 + j * 16 + (lane & 15);
                out[(size_t)row * 2048 + OFF + u * d + mi] = acc[i][j][r];
            }
}

// ---------------------------------------------------------------------------
extern "C" void kernel_launch(void* const* d_in, const int* in_sizes, int n_in,
                              void* d_out, int out_size, void* d_ws, size_t ws_size,
                              hipStream_t stream) {
    const float* x1   = (const float*)d_in[0];
    const float* x2   = (const float*)d_in[1];
    const float* W1   = (const float*)d_in[2];
    const float* W2   = (const float*)d_in[3];
    const float* Wout = (const float*)d_in[4];
    float* out = (float*)d_out;

    prep_kernel<<<B_N + 768, 256, 0, stream>>>(x1, x2, W1, W2, Wout, out);
    cmid_kernel<<<dim3(4, B_N / 16), 256, 0, stream>>>();
    out_gemm_kernel<<<dim3(B_N / 64, NKM), 256, 0, stream>>>(out);
}